// Round 2
// baseline (356.671 us; speedup 1.0000x reference)
//
#include <hip/hip_runtime.h>
#include <hip/hip_bf16.h>
#include <stdint.h>
#include <stddef.h>

typedef __attribute__((ext_vector_type(8))) short short8;
typedef __attribute__((ext_vector_type(4))) float floatx4;

#define AS_GLOBAL(p) (const __attribute__((address_space(1))) void*)(p)
#define AS_LDS(p)    (__attribute__((address_space(3))) void*)(p)

static constexpr int IN_DIM  = 4096;
static constexpr int OUT_DIM = 4096;
static constexpr int S_DIM   = 256;
static constexpr int S2      = 512;   // both branches concatenated along rank

// ---------------- fused prep: W1, W2, x->bf16 in ONE launch ----------------
// blocks [0, 2048):          W1[s,i] = v2[i] * sign(V[s,i])          (4 elem/thread)
// blocks [2048, 4096):       W2[o,s] = u1[o]*v1[s]*u2[s]*sign(U[o,s]) (4 elem/thread)
// blocks [4096, ...):        Xb = bf16(x)                             (8 elem/thread)
__global__ void prep_kernel(const float* __restrict__ V, const float* __restrict__ v2,
                            const float* __restrict__ V_R, const float* __restrict__ v2_R,
                            const float* __restrict__ U, const float* __restrict__ u1,
                            const float* __restrict__ v1, const float* __restrict__ u2,
                            const float* __restrict__ U_R, const float* __restrict__ u1_R,
                            const float* __restrict__ v1_R, const float* __restrict__ u2_R,
                            const float* __restrict__ x,
                            __hip_bfloat16* __restrict__ W1,
                            __hip_bfloat16* __restrict__ W2,
                            __hip_bfloat16* __restrict__ Xb) {
  const int bid = blockIdx.x;
  if (bid < 2048) {
    const int idx4 = (bid * 256 + threadIdx.x) * 4;   // over S2*IN_DIM
    const int i = idx4 & (IN_DIM - 1);
    const int s = idx4 >> 12;
    floatx4 w, sc;
    if (s < S_DIM) {
      w  = *(const floatx4*)(V + s * IN_DIM + i);
      sc = *(const floatx4*)(v2 + i);
    } else {
      w  = *(const floatx4*)(V_R + (s - S_DIM) * IN_DIM + i);
      sc = *(const floatx4*)(v2_R + i);
    }
    union { ushort4 v; __hip_bfloat16 h[4]; } u;
#pragma unroll
    for (int j = 0; j < 4; ++j) {
      const float sg = (w[j] > 0.f) ? 1.f : ((w[j] < 0.f) ? -1.f : 0.f);
      u.h[j] = __float2bfloat16(sg * sc[j]);
    }
    *(ushort4*)((unsigned short*)W1 + idx4) = u.v;
  } else if (bid < 4096) {
    const int idx4 = ((bid - 2048) * 256 + threadIdx.x) * 4;   // over OUT_DIM*S2
    const int s = idx4 & (S2 - 1);
    const int o = idx4 >> 9;
    floatx4 w, scs;
    float sco;
    if (s < S_DIM) {
      w   = *(const floatx4*)(U + o * S_DIM + s);
      sco = u1[o];
      const floatx4 a = *(const floatx4*)(v1 + s);
      const floatx4 b = *(const floatx4*)(u2 + s);
      scs = a * b;
    } else {
      const int ss = s - S_DIM;
      w   = *(const floatx4*)(U_R + o * S_DIM + ss);
      sco = u1_R[o];
      const floatx4 a = *(const floatx4*)(v1_R + ss);
      const floatx4 b = *(const floatx4*)(u2_R + ss);
      scs = a * b;
    }
    union { ushort4 v; __hip_bfloat16 h[4]; } u;
#pragma unroll
    for (int j = 0; j < 4; ++j) {
      const float sg = (w[j] > 0.f) ? 1.f : ((w[j] < 0.f) ? -1.f : 0.f);
      u.h[j] = __float2bfloat16(sg * sco * scs[j]);
    }
    *(ushort4*)((unsigned short*)W2 + idx4) = u.v;
  } else {
    const int idx = (bid - 4096) * 256 + threadIdx.x;   // 8 floats / thread
    const floatx4 f0 = *((const floatx4*)x + idx * 2);
    const floatx4 f1 = *((const floatx4*)x + idx * 2 + 1);
    union { short8 v; __hip_bfloat16 h[8]; } u;
    u.h[0] = __float2bfloat16(f0.x); u.h[1] = __float2bfloat16(f0.y);
    u.h[2] = __float2bfloat16(f0.z); u.h[3] = __float2bfloat16(f0.w);
    u.h[4] = __float2bfloat16(f1.x); u.h[5] = __float2bfloat16(f1.y);
    u.h[6] = __float2bfloat16(f1.z); u.h[7] = __float2bfloat16(f1.w);
    *((short8*)Xb + idx) = u.v;
  }
}

// ---------------- GEMM1: H[M,512] = Xb[M,4096] @ W1[512,4096]^T ----------------
// BM=64, BN=128, BK=64, 2 waves/block (128 thr), each wave owns a 64x64
// output tile with acc[4][4]. Rationale: the old 64x32 wave tile (acc 4x2)
// demanded 155 B/cyc/wave of LDS reads vs ~105 for 64x64 — LDS read BW is
// the binding pipe, and this cut is 1.5x. 32 MFMA/wave per barrier (was 16).
// Grid 512 -> 2 blocks/CU: two independent blocks per CU overlap each other's
// barrier drains. Double-buffered LDS: next tile's global_load_lds stay in
// flight across the whole MFMA phase. XOR-swizzled 16B-chunk layout:
// chunk(row,kc) at index row*8 + (kc ^ (row&7)).
__global__ __launch_bounds__(128)
void gemm1_kernel(const __hip_bfloat16* __restrict__ A,
                  const __hip_bfloat16* __restrict__ B,
                  __hip_bfloat16* __restrict__ C) {
  constexpr int K = IN_DIM;   // 4096
  constexpr int N = S2;       // 512
  constexpr int BM = 64, BN = 128, BK = 64;

  __shared__ __hip_bfloat16 As[2][BM * BK];   // 2 x 8 KB
  __shared__ __hip_bfloat16 Bs[2][BN * BK];   // 2 x 16 KB

  const int t = threadIdx.x;
  const int wave = t >> 6;
  const int lane = t & 63;
  const int r16 = lane & 15;
  const int quad = lane >> 4;

  // XCD swizzle: 512 blocks; XCD c handles M-tiles [c*16, c*16+16) x all 4 N-tiles.
  const int f = blockIdx.x;
  const int c = f & 7;
  const int l = f >> 3;              // [0,64)
  const int tm0 = (c * 16 + (l >> 2)) * BM;   // 128 M-tiles of 64 rows
  const int tn0 = (l & 3) * BN;
  const int wn = wave * 64;

  floatx4 acc[4][4] = {};

  auto stage = [&](int buf, int k0) {
#pragma unroll
    for (int i = 0; i < 4; ++i) {               // A: 512 chunks / 128 thr
      const int p = t + i * 128;
      const int row = p >> 3;
      const int ql = (p & 7) ^ (row & 7);
      const __hip_bfloat16* gp = A + (size_t)(tm0 + row) * K + k0 + ql * 8;
      __builtin_amdgcn_global_load_lds(AS_GLOBAL(gp), AS_LDS((char*)&As[buf][0] + p * 16), 16, 0, 0);
    }
#pragma unroll
    for (int i = 0; i < 8; ++i) {               // B: 1024 chunks / 128 thr
      const int p = t + i * 128;
      const int row = p >> 3;
      const int ql = (p & 7) ^ (row & 7);
      const __hip_bfloat16* gp = B + (size_t)(tn0 + row) * K + k0 + ql * 8;
      __builtin_amdgcn_global_load_lds(AS_GLOBAL(gp), AS_LDS((char*)&Bs[buf][0] + p * 16), 16, 0, 0);
    }
  };

  stage(0, 0);
  __syncthreads();   // one-time prologue drain

  int buf = 0;
  for (int k0 = 0; k0 < K; k0 += BK) {
    if (k0 + BK < K) stage(buf ^ 1, k0 + BK);   // in flight during MFMA phase

    const char* as = (const char*)&As[buf][0];
    const char* bs = (const char*)&Bs[buf][0];
#pragma unroll
    for (int ks = 0; ks < 2; ++ks) {
      short8 a[4], b[4];
      const int cc = ks * 4 + quad;
#pragma unroll
      for (int i = 0; i < 4; ++i) {
        const int ar = i * 16 + r16;            // wm == 0 (single wave-row)
        a[i] = *reinterpret_cast<const short8*>(as + (ar * 8 + (cc ^ (ar & 7))) * 16);
      }
#pragma unroll
      for (int j = 0; j < 4; ++j) {
        const int br = wn + j * 16 + r16;
        b[j] = *reinterpret_cast<const short8*>(bs + (br * 8 + (cc ^ (br & 7))) * 16);
      }
#pragma unroll
      for (int i = 0; i < 4; ++i)
#pragma unroll
        for (int j = 0; j < 4; ++j)
          acc[i][j] = __builtin_amdgcn_mfma_f32_16x16x32_bf16(a[i], b[j], acc[i][j], 0, 0, 0);
    }
    __syncthreads();   // drains next-tile loads (overlapped) + protects buf reuse
    buf ^= 1;
  }

#pragma unroll
  for (int i = 0; i < 4; ++i)
#pragma unroll
    for (int j = 0; j < 4; ++j)
#pragma unroll
      for (int r = 0; r < 4; ++r) {
        const int row = tm0 + i * 16 + quad * 4 + r;
        const int col = tn0 + wn + j * 16 + r16;
        C[(size_t)row * N + col] = __float2bfloat16(acc[i][j][r]);
      }
}

// ---------------- GEMM2: Y[M,4096] = H[M,512] @ W2[4096,512]^T + bias ----------------
// BM=128, BN=128, BK=64 -> 8 K-iterations, 32 MFMA/wave per barrier.
// DOUBLE-BUFFERED: the old single-buffer loop exposed a full vmcnt(0)
// stage drain (~L2 latency) on every one of the 8 iterations. Cost: LDS
// 32->64 KB, occupancy 3->2 blocks/CU; the staged loads now fly across the
// whole MFMA phase instead.
__global__ __launch_bounds__(256, 2)
void gemm2_kernel(const __hip_bfloat16* __restrict__ A,
                  const __hip_bfloat16* __restrict__ B,
                  const float* __restrict__ bias,
                  float* __restrict__ C) {
  constexpr int K = S2;        // 512
  constexpr int N = OUT_DIM;   // 4096
  constexpr int BM = 128, BN = 128, BK = 64;

  __shared__ __hip_bfloat16 As[2][BM * BK];   // 2 x 16 KB
  __shared__ __hip_bfloat16 Bs[2][BN * BK];   // 2 x 16 KB

  const int t = threadIdx.x;
  const int wave = t >> 6;
  const int lane = t & 63;
  const int r16 = lane & 15;
  const int quad = lane >> 4;

  // XCD swizzle: 2048 blocks; XCD c handles M-tiles [c*8,c*8+8) x all 32 N-tiles.
  const int f = blockIdx.x;
  const int c = f & 7;
  const int l = f >> 3;              // [0,256)
  const int tm0 = (c * 8 + (l >> 5)) * BM;
  const int tn0 = (l & 31) * BN;

  const int wm = (wave & 1) * 64;
  const int wn = (wave >> 1) * 64;

  floatx4 acc[4][4] = {};

  auto stage = [&](int buf, int k0) {
#pragma unroll
    for (int i = 0; i < 4; ++i) {
      const int p = t + i * 256;
      const int row = p >> 3;
      const int ql = (p & 7) ^ (row & 7);
      const __hip_bfloat16* gp = A + (size_t)(tm0 + row) * K + k0 + ql * 8;
      __builtin_amdgcn_global_load_lds(AS_GLOBAL(gp), AS_LDS((char*)&As[buf][0] + p * 16), 16, 0, 0);
    }
#pragma unroll
    for (int i = 0; i < 4; ++i) {
      const int p = t + i * 256;
      const int row = p >> 3;
      const int ql = (p & 7) ^ (row & 7);
      const __hip_bfloat16* gp = B + (size_t)(tn0 + row) * K + k0 + ql * 8;
      __builtin_amdgcn_global_load_lds(AS_GLOBAL(gp), AS_LDS((char*)&Bs[buf][0] + p * 16), 16, 0, 0);
    }
  };

  stage(0, 0);
  __syncthreads();   // prologue drain

  int buf = 0;
  for (int k0 = 0; k0 < K; k0 += BK) {
    if (k0 + BK < K) stage(buf ^ 1, k0 + BK);   // in flight during MFMA phase

    const char* as = (const char*)&As[buf][0];
    const char* bs = (const char*)&Bs[buf][0];
#pragma unroll
    for (int ks = 0; ks < 2; ++ks) {
      short8 a[4], b[4];
      const int cc = ks * 4 + quad;
#pragma unroll
      for (int i = 0; i < 4; ++i) {
        const int ar = wm + i * 16 + r16;
        a[i] = *reinterpret_cast<const short8*>(as + (ar * 8 + (cc ^ (ar & 7))) * 16);
      }
#pragma unroll
      for (int j = 0; j < 4; ++j) {
        const int br = wn + j * 16 + r16;
        b[j] = *reinterpret_cast<const short8*>(bs + (br * 8 + (cc ^ (br & 7))) * 16);
      }
#pragma unroll
      for (int i = 0; i < 4; ++i)
#pragma unroll
        for (int j = 0; j < 4; ++j)
          acc[i][j] = __builtin_amdgcn_mfma_f32_16x16x32_bf16(a[i], b[j], acc[i][j], 0, 0, 0);
    }
    __syncthreads();
    buf ^= 1;
  }

  // epilogue: bias + fp32 store
  float bi[4];
#pragma unroll
  for (int j = 0; j < 4; ++j) bi[j] = bias[tn0 + wn + j * 16 + r16];

#pragma unroll
  for (int i = 0; i < 4; ++i)
#pragma unroll
    for (int j = 0; j < 4; ++j)
#pragma unroll
      for (int r = 0; r < 4; ++r) {
        const int row = tm0 + wm + i * 16 + quad * 4 + r;
        const int col = tn0 + wn + j * 16 + r16;
        C[(size_t)row * N + col] = acc[i][j][r] + bi[j];
      }
}

// ---------------- launch ----------------
extern "C" void kernel_launch(void* const* d_in, const int* in_sizes, int n_in,
                              void* d_out, int out_size, void* d_ws, size_t ws_size,
                              hipStream_t stream) {
  const float* x    = (const float*)d_in[0];
  const float* V    = (const float*)d_in[1];
  const float* U    = (const float*)d_in[2];
  const float* v1   = (const float*)d_in[3];
  const float* v2   = (const float*)d_in[4];
  const float* u1   = (const float*)d_in[5];
  const float* u2   = (const float*)d_in[6];
  const float* V_R  = (const float*)d_in[7];
  const float* U_R  = (const float*)d_in[8];
  const float* v1_R = (const float*)d_in[9];
  const float* v2_R = (const float*)d_in[10];
  const float* u1_R = (const float*)d_in[11];
  const float* u2_R = (const float*)d_in[12];
  const float* bias = (const float*)d_in[13];
  float* out = (float*)d_out;

  const int M = in_sizes[0] / IN_DIM;   // 8192

  char* ws = (char*)d_ws;
  __hip_bfloat16* W1 = (__hip_bfloat16*)ws;                                   // 4 MB
  __hip_bfloat16* W2 = (__hip_bfloat16*)(ws + (size_t)4 * 1024 * 1024);       // 4 MB
  __hip_bfloat16* H  = (__hip_bfloat16*)(ws + (size_t)8 * 1024 * 1024);       // M*512*2 = 8 MB
  __hip_bfloat16* Xb = (__hip_bfloat16*)(ws + (size_t)16 * 1024 * 1024);      // M*4096*2 = 64 MB

  // fused prep: 2048 (W1) + 2048 (W2) + M*IN/(8*256) (cvt) blocks
  const int cvt_blocks = (M * IN_DIM) / (8 * 256);
  prep_kernel<<<4096 + cvt_blocks, 256, 0, stream>>>(
      V, v2, V_R, v2_R, U, u1, v1, u2, U_R, u1_R, v1_R, u2_R, x, W1, W2, Xb);

  // GEMM1: (M/64) x (512/128) = 128 x 4 = 512 blocks, 128 thr, XCD-swizzled
  gemm1_kernel<<<(M / 64) * (S2 / 128), 128, 0, stream>>>(Xb, W1, H);

  // GEMM2: (M/128) x (4096/128) = 64 x 32 = 2048 blocks
  gemm2_kernel<<<(M / 128) * (OUT_DIM / 128), 256, 0, stream>>>(H, W2, bias, out);
}